// Round 23
// baseline (198.582 us; speedup 1.0000x reference)
//
#include <hip/hip_runtime.h>
#include <math.h>

#define DMODEL 256
#define NHEAD 8
#define NLVL 3
#define NPTS 4
#define HDIM 32
#define QLEN 10000
#define BATCH 4
#define NQ (BATCH * QLEN)

typedef __attribute__((ext_vector_type(8))) short bf16x8;
typedef __attribute__((ext_vector_type(4))) float f32x4;

__device__ __forceinline__ float tanh_fast(float x)
{
    const float ax = fabsf(x);
    const float e  = __expf(-2.f * ax);
    const float t  = (1.f - e) / (1.f + e);
    return copysignf(t, x);
}

__device__ __forceinline__ unsigned short f2bf(float f)
{
    unsigned int u = __float_as_uint(f);
    u = (u + 0x7FFFu + ((u >> 16) & 1u)) >> 16;
    return (unsigned short)u;
}

__device__ __forceinline__ float bf2f(unsigned short s)
{
    return __uint_as_float(((unsigned int)s) << 16);
}

// ---------------------------------------------------------------------------
// K0: weight prep (once).  Pre-swizzled layouts (validated R18).
// ---------------------------------------------------------------------------
__global__ __launch_bounds__(256) void wprep_kernel(
    const float* __restrict__ Woff, const float* __restrict__ Wattn,
    const float* __restrict__ Wout, const float* __restrict__ Wval,
    unsigned short* __restrict__ WTs, unsigned short* __restrict__ WoT,
    unsigned short* __restrict__ WvSh, unsigned short* __restrict__ WvSl)
{
    const int k  = threadIdx.x;
    const int n  = blockIdx.x;
    const int ks = k >> 5;
    const int g  = (k >> 3) & 3;
    const int j  = k & 7;
    if (n < 288) {
        const float w = (n < 192) ? Woff[(size_t)k * 192 + n]
                                  : Wattn[(size_t)k * 96 + (n - 192)];
        const unsigned short hi = f2bf(w);
        const unsigned short lo = f2bf(w - bf2f(hi));
        const int nt = n >> 4, c = n & 15;
        const size_t base = (size_t)ks * 18432 + (size_t)nt * 512
                          + g * 128 + c * 8 + j;
        WTs[base]        = hi;    // hl = 0
        WTs[base + 9216] = lo;    // hl = 1 (offset 9216 shorts)
    } else if (n < 544) {
        const int nn = n - 288;
        WoT[(size_t)nn * 256 + k] = f2bf(Wout[(size_t)k * 256 + nn]);
    } else {
        const int nn = n - 544;
        const float w = Wval[(size_t)k * 256 + nn];
        const unsigned short hi = f2bf(w);
        const int nc = nn >> 4, c = nn & 15;
        const size_t idx = (size_t)nc * 4096 + (size_t)ks * 512
                         + g * 128 + c * 8 + j;
        WvSh[idx] = hi;
        WvSl[idx] = f2bf(w - bf2f(hi));
    }
}

// ---------------------------------------------------------------------------
// K1: value projection via bf16 MFMA, 32-pos tiles (validated R18).
// Output HEAD-MAJOR v[b][h][pos][32].
// ---------------------------------------------------------------------------
__global__ __launch_bounds__(256) void vproj_kernel(
    const float* __restrict__ feat0, const float* __restrict__ feat1,
    const float* __restrict__ feat2,
    const unsigned short* __restrict__ WvSh, const unsigned short* __restrict__ WvSl,
    const float* __restrict__ bv,
    unsigned short* __restrict__ v0, unsigned short* __restrict__ v1,
    unsigned short* __restrict__ v2)
{
    __shared__ short As[32 * 32 * 8];   // [kc][pos][8] = 16 KB

    const int bx = blockIdx.x;
    const int b  = blockIdx.y;

    const float* feat;
    unsigned short* vout;
    int HW, pos0;
    if (bx < 313)      { feat = feat0; vout = v0; HW = 10000; pos0 = bx * 32; }
    else if (bx < 392) { feat = feat1; vout = v1; HW = 2500;  pos0 = (bx - 313) * 32; }
    else               { feat = feat2; vout = v2; HW = 625;   pos0 = (bx - 392) * 32; }

    const int tid  = threadIdx.x;
    const int wv   = tid >> 6;
    const int lane = tid & 63;
    const int c    = lane & 15;
    const int g    = lane >> 4;

    const int sp  = tid & 31;
    const int kc8 = tid >> 5;
    const bool pv = (pos0 + sp) < HW;
    const float* fcol = feat + (size_t)b * DMODEL * HW + pos0 + sp;

#pragma unroll
    for (int i = 0; i < 4; ++i) {
        const int kc = kc8 + 8 * i;
        short h8[8];
#pragma unroll
        for (int j = 0; j < 8; ++j) {
            const float f = pv ? fcol[(size_t)(kc * 8 + j) * HW] : 0.f;
            h8[j] = (short)f2bf(f);
        }
        *(bf16x8*)&As[((size_t)kc * 32 + sp) * 8] = *(bf16x8*)h8;
    }
    __syncthreads();

    f32x4 acc[2][4];
#pragma unroll
    for (int mt = 0; mt < 2; ++mt)
#pragma unroll
        for (int nt = 0; nt < 4; ++nt)
            acc[mt][nt] = (f32x4){0.f, 0.f, 0.f, 0.f};

#pragma unroll
    for (int ks = 0; ks < 8; ++ks) {
        bf16x8 a[2];
#pragma unroll
        for (int mt = 0; mt < 2; ++mt)
            a[mt] = *(const bf16x8*)&As[((size_t)(ks * 4 + g) * 32 + mt * 16 + c) * 8];
        bf16x8 bh[4], bl[4];
#pragma unroll
        for (int nt = 0; nt < 4; ++nt) {
            const size_t off = (size_t)(wv * 4 + nt) * 4096 + (size_t)ks * 512
                             + g * 128 + c * 8;
            bh[nt] = *(const bf16x8*)(WvSh + off);
            bl[nt] = *(const bf16x8*)(WvSl + off);
        }
#pragma unroll
        for (int mt = 0; mt < 2; ++mt)
#pragma unroll
            for (int nt = 0; nt < 4; ++nt) {
                acc[mt][nt] = __builtin_amdgcn_mfma_f32_16x16x32_bf16(
                    a[mt], bh[nt], acc[mt][nt], 0, 0, 0);
                acc[mt][nt] = __builtin_amdgcn_mfma_f32_16x16x32_bf16(
                    a[mt], bl[nt], acc[mt][nt], 0, 0, 0);
            }
    }

    unsigned short* vbp = vout + (size_t)b * NHEAD * HW * 32;
#pragma unroll
    for (int nt = 0; nt < 4; ++nt) {
        const int col  = wv * 64 + nt * 16 + c;
        const int hh   = col >> 5;
        const int cc   = col & 31;
        const float bias = bv[col];
#pragma unroll
        for (int mt = 0; mt < 2; ++mt) {
#pragma unroll
            for (int j = 0; j < 4; ++j) {
                const int p = mt * 16 + g * 4 + j;
                if (pos0 + p < HW)
                    vbp[((size_t)hh * HW + pos0 + p) * 32 + cc] =
                        f2bf(acc[mt][nt][j] + bias);
            }
        }
    }
}

// ---------------------------------------------------------------------------
// K2: query-side GEMM, direct-global B, 64 ROWS/BLOCK (acc[4][5]): halves
// B-fragment traffic and doubles MFMA per B-load vs the R19 32-row version.
// ---------------------------------------------------------------------------
__global__ __launch_bounds__(256) void qgemm_kernel(
    const float* __restrict__ query,
    const unsigned short* __restrict__ WTs,
    float* __restrict__ logits)
{
    const int tid  = threadIdx.x;
    const int wt   = tid >> 6;
    const int lane = tid & 63;
    const int c    = lane & 15;
    const int g    = lane >> 4;
    const int row0 = blockIdx.x * 64;

    const float* qr[4];
#pragma unroll
    for (int t = 0; t < 4; ++t)
        qr[t] = query + (size_t)(row0 + t * 16 + c) * 256 + 8 * g;

    f32x4 acc[4][5];
#pragma unroll
    for (int t = 0; t < 4; ++t)
#pragma unroll
        for (int i = 0; i < 5; ++i) acc[t][i] = (f32x4){0.f, 0.f, 0.f, 0.f};

#pragma unroll
    for (int ks = 0; ks < 8; ++ks) {
        bf16x8 a_hi[4], a_lo[4];
#pragma unroll
        for (int t = 0; t < 4; ++t) {
            const float4 q0 = *(const float4*)(qr[t] + ks * 32);
            const float4 q1 = *(const float4*)(qr[t] + ks * 32 + 4);
            const float av[8] = {q0.x, q0.y, q0.z, q0.w, q1.x, q1.y, q1.z, q1.w};
#pragma unroll
            for (int j = 0; j < 8; ++j) {
                const unsigned short hi = f2bf(av[j]);
                a_hi[t][j] = (short)hi;
                a_lo[t][j] = (short)f2bf(av[j] - bf2f(hi));
            }
        }

#pragma unroll
        for (int i = 0; i < 5; ++i) {
            const int nt = wt + 4 * i;
            if (nt < 18) {
                const unsigned short* bp = WTs + (size_t)ks * 18432
                                         + (size_t)nt * 512 + g * 128 + c * 8;
                const bf16x8 b_hi = *(const bf16x8*)bp;
                const bf16x8 b_lo = *(const bf16x8*)(bp + 9216);
#pragma unroll
                for (int t = 0; t < 4; ++t) {
                    acc[t][i] = __builtin_amdgcn_mfma_f32_16x16x32_bf16(
                        a_hi[t], b_hi, acc[t][i], 0, 0, 0);
                    acc[t][i] = __builtin_amdgcn_mfma_f32_16x16x32_bf16(
                        a_lo[t], b_hi, acc[t][i], 0, 0, 0);
                    acc[t][i] = __builtin_amdgcn_mfma_f32_16x16x32_bf16(
                        a_hi[t], b_lo, acc[t][i], 0, 0, 0);
                }
            }
        }
    }

#pragma unroll
    for (int i = 0; i < 5; ++i) {
        const int nt = wt + 4 * i;
        if (nt < 18) {
            const int col = nt * 16 + c;
#pragma unroll
            for (int t = 0; t < 4; ++t)
#pragma unroll
                for (int j = 0; j < 4; ++j)
                    logits[(size_t)(row0 + t * 16 + 4 * g + j) * 288 + col] =
                        acc[t][i][j];
        }
    }
}

// ---------------------------------------------------------------------------
// K3: sampler.  4-LANE (q,h) groups, 16B (8-channel) corner loads: wave
// covers 16 queries -> total gather VMEM instructions HALVE.  Lane co owns
// exactly one point per level (pt = 4l+co).  3 bpermutes/point + imm-offset
// corner loads (R21/R22 structure); guard region absorbs weight-0 spills.
// ---------------------------------------------------------------------------
__global__ __launch_bounds__(256) void sample_kernel(
    const float* __restrict__ logits,
    const float* __restrict__ ref,
    const float* __restrict__ boff, const float* __restrict__ battn,
    const unsigned short* __restrict__ v0,
    const unsigned short* __restrict__ v1,
    const unsigned short* __restrict__ v2,
    unsigned short* __restrict__ outp)
{
    const int tid  = threadIdx.x;
    const int wv   = tid >> 6;
    const int lane = tid & 63;
    const int qd   = lane >> 2;          // query within wave (0..15)
    const int co   = lane & 3;           // channel quad: ch co*8..co*8+7

    const int id = blockIdx.x;           // 0..5023
    const int h  = id & 7;               // XCD key
    const int m  = id >> 3;              // 0..627
    const int b  = m / 157;
    const int n  = m - b * 157;
    const int q  = n * 64 + wv * 16 + qd;
    if (q >= QLEN) return;               // 4-lane group exits together
    const int qq = b * QLEN + q;

    const float* lgq  = logits + (size_t)qq * 288;
    const int bpbase  = (lane & 60) * 4; // byte index of group lane 0

    // ---- distributed softmax: lane co owns logits {co, 4+co, 8+co} ----
    const float a0l = lgq[192 + h * 12 + co]     + battn[h * 12 + co];
    const float a1l = lgq[192 + h * 12 + 4 + co] + battn[h * 12 + 4 + co];
    const float a2l = lgq[192 + h * 12 + 8 + co] + battn[h * 12 + 8 + co];
    float mx = fmaxf(fmaxf(a0l, a1l), a2l);
#pragma unroll
    for (int msk = 1; msk < 4; msk <<= 1)
        mx = fmaxf(mx, __shfl_xor(mx, msk, 4));
    const float e0 = __expf(a0l - mx);
    const float e1 = __expf(a1l - mx);
    const float e2 = __expf(a2l - mx);
    float sm = e0 + e1 + e2;
#pragma unroll
    for (int msk = 1; msk < 4; msk <<= 1)
        sm += __shfl_xor(sm, msk, 4);
    const float inv = 1.f / sm;

    const float refx = ref[(size_t)qq * 2 + 0];
    const float refy = ref[(size_t)qq * 2 + 1];

    // ---- owner: one point per level; packed weights + biased base ----
    unsigned int opkA[3], opkB[3], opkI[3];
    const float el[3] = {e0, e1, e2};
#pragma unroll
    for (int s = 0; s < 3; ++s) {
        const int pt = s * 4 + co;
        const int Wl = (s == 0) ? 100 : (s == 1) ? 50 : 25;
        const float aw  = el[s] * inv;
        const float lgx = lgq[h * 24 + 2 * pt]     + boff[h * 24 + 2 * pt];
        const float lgy = lgq[h * 24 + 2 * pt + 1] + boff[h * 24 + 2 * pt + 1];
        const float x = (refx + 0.5f * tanh_fast(lgx)) * (float)Wl - 0.5f;
        const float y = (refy + 0.5f * tanh_fast(lgy)) * (float)Wl - 0.5f;
        const float xf = floorf(x), yf = floorf(y);
        const int   x0i = (int)xf, y0i = (int)yf;
        const float wx = x - xf, wy = y - yf;

        float w4[4];
#pragma unroll
        for (int cy = 0; cy < 2; ++cy) {
#pragma unroll
            for (int cx = 0; cx < 2; ++cx) {
                const int xi = x0i + cx, yi = y0i + cy;
                const bool valid = (xi >= 0) & (xi < Wl) & (yi >= 0) & (yi < Wl);
                w4[cy * 2 + cx] = valid
                    ? aw * (cx ? wx : 1.f - wx) * (cy ? wy : 1.f - wy) : 0.f;
            }
        }
        const int xb = min(max(x0i, -1), Wl - 1);
        const int yb = min(max(y0i, -1), Wl - 1);
        opkI[s] = (unsigned int)(yb * Wl + xb + Wl + 1);       // >= 0
        opkA[s] = ((unsigned int)f2bf(w4[0]) << 16) | f2bf(w4[1]);
        opkB[s] = ((unsigned int)f2bf(w4[2]) << 16) | f2bf(w4[3]);
    }

    // ---- gather: 3 bpermutes/point, 16B imm-offset corner loads ----
    float o0 = 0.f, o1 = 0.f, o2 = 0.f, o3 = 0.f;
    float o4 = 0.f, o5 = 0.f, o6 = 0.f, o7 = 0.f;

#pragma unroll
    for (int l = 0; l < 3; ++l) {
        const int Wl = (l == 0) ? 100 : (l == 1) ? 50 : 25;
        const int HW = Wl * Wl;
        const unsigned short* vh =
            ((l == 0) ? v0 : (l == 1) ? v1 : v2) +
            ((size_t)(b * NHEAD + h) * HW) * 32;
        const unsigned short* vha = vh + co * 8 - (size_t)(Wl + 1) * 32;

#pragma unroll
        for (int p = 0; p < 4; ++p) {
            const int a0 = bpbase + 4 * p;    // owner lane of point (l,p)
            const unsigned int pA = (unsigned int)__builtin_amdgcn_ds_bpermute(
                a0, (int)opkA[l]);
            const unsigned int pB = (unsigned int)__builtin_amdgcn_ds_bpermute(
                a0, (int)opkB[l]);
            const int pki = __builtin_amdgcn_ds_bpermute(a0, (int)opkI[l]);

            const float w00 = __uint_as_float(pA & 0xffff0000u);
            const float w01 = __uint_as_float(pA << 16);
            const float w10 = __uint_as_float(pB & 0xffff0000u);
            const float w11 = __uint_as_float(pB << 16);

            const unsigned short* bp = vha + (size_t)pki * 32;
#pragma unroll
            for (int cn = 0; cn < 4; ++cn) {
                const int off = (cn & 1) * 32 + (cn >> 1) * Wl * 32;
                const float cw = (cn == 0) ? w00 : (cn == 1) ? w01
                               : (cn == 2) ? w10 : w11;
                const uint4 u = *(const uint4*)(bp + off);
                o0 = fmaf(cw, __uint_as_float(u.x << 16), o0);
                o1 = fmaf(cw, __uint_as_float(u.x & 0xffff0000u), o1);
                o2 = fmaf(cw, __uint_as_float(u.y << 16), o2);
                o3 = fmaf(cw, __uint_as_float(u.y & 0xffff0000u), o3);
                o4 = fmaf(cw, __uint_as_float(u.z << 16), o4);
                o5 = fmaf(cw, __uint_as_float(u.z & 0xffff0000u), o5);
                o6 = fmaf(cw, __uint_as_float(u.w << 16), o6);
                o7 = fmaf(cw, __uint_as_float(u.w & 0xffff0000u), o7);
            }
        }
    }

    uint4 outv;
    outv.x = (unsigned int)f2bf(o0) | ((unsigned int)f2bf(o1) << 16);
    outv.y = (unsigned int)f2bf(o2) | ((unsigned int)f2bf(o3) << 16);
    outv.z = (unsigned int)f2bf(o4) | ((unsigned int)f2bf(o5) << 16);
    outv.w = (unsigned int)f2bf(o6) | ((unsigned int)f2bf(o7) << 16);
    *(uint4*)(outp + (size_t)qq * 256 + h * 32 + co * 8) = outv;
}

// ---------------------------------------------------------------------------
// K4: output projection via bf16 MFMA (validated R7).
// ---------------------------------------------------------------------------
__global__ __launch_bounds__(256) void outproj_kernel(
    const unsigned short* __restrict__ A, const unsigned short* __restrict__ WoT,
    const float* __restrict__ bo, float* __restrict__ out)
{
    const int tid  = threadIdx.x;
    const int wave = tid >> 6;
    const int lane = tid & 63;
    const int c    = lane & 15;
    const int g    = lane >> 4;
    const int row0 = blockIdx.x * 64;
    const int n0   = wave * 64;

    f32x4 acc[4][4];
#pragma unroll
    for (int mt = 0; mt < 4; ++mt)
#pragma unroll
        for (int nt = 0; nt < 4; ++nt)
            acc[mt][nt] = (f32x4){0.f, 0.f, 0.f, 0.f};

    const unsigned short* Abase = A   + (size_t)(row0 + c) * 256 + 8 * g;
    const unsigned short* Bbase = WoT + (size_t)(n0   + c) * 256 + 8 * g;

#pragma unroll
    for (int ks = 0; ks < 8; ++ks) {
        bf16x8 a[4], bvec[4];
#pragma unroll
        for (int t = 0; t < 4; ++t) {
            a[t]    = *(const bf16x8*)(Abase + (size_t)t * 16 * 256 + ks * 32);
            bvec[t] = *(const bf16x8*)(Bbase + (size_t)t * 16 * 256 + ks * 32);
        }
#pragma unroll
        for (int mt = 0; mt < 4; ++mt)
#pragma unroll
            for (int nt = 0; nt < 4; ++nt)
                acc[mt][nt] = __builtin_amdgcn_mfma_f32_16x16x32_bf16(
                    a[mt], bvec[nt], acc[mt][nt], 0, 0, 0);
    }

#pragma unroll
    for (int nt = 0; nt < 4; ++nt) {
        const int col  = n0 + nt * 16 + c;
        const float bias = bo[col];
#pragma unroll
        for (int mt = 0; mt < 4; ++mt) {
#pragma unroll
            for (int j = 0; j < 4; ++j) {
                const int row = row0 + mt * 16 + g * 4 + j;
                out[(size_t)row * 256 + col] = acc[mt][nt][j] + bias;
            }
        }
    }
}

// ---------------------------------------------------------------------------
extern "C" void kernel_launch(void* const* d_in, const int* in_sizes, int n_in,
                              void* d_out, int out_size, void* d_ws, size_t ws_size,
                              hipStream_t stream)
{
    const float* query  = (const float*)d_in[0];
    const float* value0 = (const float*)d_in[1];
    const float* value1 = (const float*)d_in[2];
    const float* value2 = (const float*)d_in[3];
    const float* refpts = (const float*)d_in[4];
    const float* Woff   = (const float*)d_in[5];
    const float* boff   = (const float*)d_in[6];
    const float* Wattn  = (const float*)d_in[7];
    const float* battn  = (const float*)d_in[8];
    const float* Wval   = (const float*)d_in[9];
    const float* bval   = (const float*)d_in[10];
    const float* Wout   = (const float*)d_in[11];
    const float* bout   = (const float*)d_in[12];
    float* out = (float*)d_out;

    // workspace: logits 46.08 + GUARD 8KB + v 26.88 + A_bf 20.48 + weights
    // ~0.7 = ~94.2 MB.  GUARD absorbs weight-0 front-spill reads.
    float*          logits = (float*)d_ws;
    unsigned short* guard = (unsigned short*)(logits + (size_t)NQ * 288);
    unsigned short* v0   = guard + 4096;              // 8 KB guard
    unsigned short* v1   = v0 + (size_t)BATCH * 10000 * 256;
    unsigned short* v2   = v1 + (size_t)BATCH * 2500  * 256;
    unsigned short* A_bf = v2 + (size_t)BATCH * 625   * 256;
    unsigned short* WoT  = A_bf + (size_t)NQ * 256;
    unsigned short* WTs  = WoT + (size_t)256 * 256;        // 147456 shorts
    unsigned short* WvSh = WTs + (size_t)147456;
    unsigned short* WvSl = WvSh + (size_t)65536;

    wprep_kernel<<<800, 256, 0, stream>>>(Woff, Wattn, Wout, Wval,
                                          WTs, WoT, WvSh, WvSl);

    vproj_kernel<<<dim3(412, BATCH), 256, 0, stream>>>(
        value0, value1, value2, WvSh, WvSl, bval, v0, v1, v2);

    qgemm_kernel<<<NQ / 64, 256, 0, stream>>>(query, WTs, logits);

    sample_kernel<<<8 * 157 * BATCH, 256, 0, stream>>>(
        logits, refpts, boff, battn, v0, v1, v2, A_bf);

    outproj_kernel<<<NQ / 64, 256, 0, stream>>>(A_bf, WoT, bout, out);
}

// Round 24
// 189.659 us; speedup vs baseline: 1.0470x; 1.0470x over previous
//
#include <hip/hip_runtime.h>
#include <math.h>

#define DMODEL 256
#define NHEAD 8
#define NLVL 3
#define NPTS 4
#define HDIM 32
#define QLEN 10000
#define BATCH 4
#define NQ (BATCH * QLEN)

typedef __attribute__((ext_vector_type(8))) short bf16x8;
typedef __attribute__((ext_vector_type(4))) float f32x4;

__device__ __forceinline__ float tanh_fast(float x)
{
    const float ax = fabsf(x);
    const float e  = __expf(-2.f * ax);
    const float t  = (1.f - e) / (1.f + e);
    return copysignf(t, x);
}

__device__ __forceinline__ unsigned short f2bf(float f)
{
    unsigned int u = __float_as_uint(f);
    u = (u + 0x7FFFu + ((u >> 16) & 1u)) >> 16;
    return (unsigned short)u;
}

__device__ __forceinline__ float bf2f(unsigned short s)
{
    return __uint_as_float(((unsigned int)s) << 16);
}

// ---------------------------------------------------------------------------
// K0: weight prep (once).  Pre-swizzled layouts (validated R18).
// ---------------------------------------------------------------------------
__global__ __launch_bounds__(256) void wprep_kernel(
    const float* __restrict__ Woff, const float* __restrict__ Wattn,
    const float* __restrict__ Wout, const float* __restrict__ Wval,
    unsigned short* __restrict__ WTs, unsigned short* __restrict__ WoT,
    unsigned short* __restrict__ WvSh, unsigned short* __restrict__ WvSl)
{
    const int k  = threadIdx.x;
    const int n  = blockIdx.x;
    const int ks = k >> 5;
    const int g  = (k >> 3) & 3;
    const int j  = k & 7;
    if (n < 288) {
        const float w = (n < 192) ? Woff[(size_t)k * 192 + n]
                                  : Wattn[(size_t)k * 96 + (n - 192)];
        const unsigned short hi = f2bf(w);
        const unsigned short lo = f2bf(w - bf2f(hi));
        const int nt = n >> 4, c = n & 15;
        const size_t base = (size_t)ks * 18432 + (size_t)nt * 512
                          + g * 128 + c * 8 + j;
        WTs[base]        = hi;    // hl = 0
        WTs[base + 9216] = lo;    // hl = 1 (offset 9216 shorts)
    } else if (n < 544) {
        const int nn = n - 288;
        WoT[(size_t)nn * 256 + k] = f2bf(Wout[(size_t)k * 256 + nn]);
    } else {
        const int nn = n - 544;
        const float w = Wval[(size_t)k * 256 + nn];
        const unsigned short hi = f2bf(w);
        const int nc = nn >> 4, c = nn & 15;
        const size_t idx = (size_t)nc * 4096 + (size_t)ks * 512
                         + g * 128 + c * 8 + j;
        WvSh[idx] = hi;
        WvSl[idx] = f2bf(w - bf2f(hi));
    }
}

// ---------------------------------------------------------------------------
// K1: value projection via bf16 MFMA, 32-pos tiles (validated R18).
// Output HEAD-MAJOR v[b][h][pos][32].
// ---------------------------------------------------------------------------
__global__ __launch_bounds__(256) void vproj_kernel(
    const float* __restrict__ feat0, const float* __restrict__ feat1,
    const float* __restrict__ feat2,
    const unsigned short* __restrict__ WvSh, const unsigned short* __restrict__ WvSl,
    const float* __restrict__ bv,
    unsigned short* __restrict__ v0, unsigned short* __restrict__ v1,
    unsigned short* __restrict__ v2)
{
    __shared__ short As[32 * 32 * 8];   // [kc][pos][8] = 16 KB

    const int bx = blockIdx.x;
    const int b  = blockIdx.y;

    const float* feat;
    unsigned short* vout;
    int HW, pos0;
    if (bx < 313)      { feat = feat0; vout = v0; HW = 10000; pos0 = bx * 32; }
    else if (bx < 392) { feat = feat1; vout = v1; HW = 2500;  pos0 = (bx - 313) * 32; }
    else               { feat = feat2; vout = v2; HW = 625;   pos0 = (bx - 392) * 32; }

    const int tid  = threadIdx.x;
    const int wv   = tid >> 6;
    const int lane = tid & 63;
    const int c    = lane & 15;
    const int g    = lane >> 4;

    const int sp  = tid & 31;
    const int kc8 = tid >> 5;
    const bool pv = (pos0 + sp) < HW;
    const float* fcol = feat + (size_t)b * DMODEL * HW + pos0 + sp;

#pragma unroll
    for (int i = 0; i < 4; ++i) {
        const int kc = kc8 + 8 * i;
        short h8[8];
#pragma unroll
        for (int j = 0; j < 8; ++j) {
            const float f = pv ? fcol[(size_t)(kc * 8 + j) * HW] : 0.f;
            h8[j] = (short)f2bf(f);
        }
        *(bf16x8*)&As[((size_t)kc * 32 + sp) * 8] = *(bf16x8*)h8;
    }
    __syncthreads();

    f32x4 acc[2][4];
#pragma unroll
    for (int mt = 0; mt < 2; ++mt)
#pragma unroll
        for (int nt = 0; nt < 4; ++nt)
            acc[mt][nt] = (f32x4){0.f, 0.f, 0.f, 0.f};

#pragma unroll
    for (int ks = 0; ks < 8; ++ks) {
        bf16x8 a[2];
#pragma unroll
        for (int mt = 0; mt < 2; ++mt)
            a[mt] = *(const bf16x8*)&As[((size_t)(ks * 4 + g) * 32 + mt * 16 + c) * 8];
        bf16x8 bh[4], bl[4];
#pragma unroll
        for (int nt = 0; nt < 4; ++nt) {
            const size_t off = (size_t)(wv * 4 + nt) * 4096 + (size_t)ks * 512
                             + g * 128 + c * 8;
            bh[nt] = *(const bf16x8*)(WvSh + off);
            bl[nt] = *(const bf16x8*)(WvSl + off);
        }
#pragma unroll
        for (int mt = 0; mt < 2; ++mt)
#pragma unroll
            for (int nt = 0; nt < 4; ++nt) {
                acc[mt][nt] = __builtin_amdgcn_mfma_f32_16x16x32_bf16(
                    a[mt], bh[nt], acc[mt][nt], 0, 0, 0);
                acc[mt][nt] = __builtin_amdgcn_mfma_f32_16x16x32_bf16(
                    a[mt], bl[nt], acc[mt][nt], 0, 0, 0);
            }
    }

    unsigned short* vbp = vout + (size_t)b * NHEAD * HW * 32;
#pragma unroll
    for (int nt = 0; nt < 4; ++nt) {
        const int col  = wv * 64 + nt * 16 + c;
        const int hh   = col >> 5;
        const int cc   = col & 31;
        const float bias = bv[col];
#pragma unroll
        for (int mt = 0; mt < 2; ++mt) {
#pragma unroll
            for (int j = 0; j < 4; ++j) {
                const int p = mt * 16 + g * 4 + j;
                if (pos0 + p < HW)
                    vbp[((size_t)hh * HW + pos0 + p) * 32 + cc] =
                        f2bf(acc[mt][nt][j] + bias);
            }
        }
    }
}

// ---------------------------------------------------------------------------
// K2: query-side GEMM, direct-global B, 32 rows/block (validated R19/R22).
// No LDS, no barriers; B-fragments straight from pre-swizzled WTs.
// ---------------------------------------------------------------------------
__global__ __launch_bounds__(256) void qgemm_kernel(
    const float* __restrict__ query,
    const unsigned short* __restrict__ WTs,
    float* __restrict__ logits)
{
    const int tid  = threadIdx.x;
    const int wt   = tid >> 6;
    const int lane = tid & 63;
    const int c    = lane & 15;
    const int g    = lane >> 4;
    const int row0 = blockIdx.x * 32;

    const float* qr[2];
#pragma unroll
    for (int t = 0; t < 2; ++t)
        qr[t] = query + (size_t)(row0 + t * 16 + c) * 256 + 8 * g;

    f32x4 acc[2][5];
#pragma unroll
    for (int t = 0; t < 2; ++t)
#pragma unroll
        for (int i = 0; i < 5; ++i) acc[t][i] = (f32x4){0.f, 0.f, 0.f, 0.f};

#pragma unroll
    for (int ks = 0; ks < 8; ++ks) {
        bf16x8 a_hi[2], a_lo[2];
#pragma unroll
        for (int t = 0; t < 2; ++t) {
            const float4 q0 = *(const float4*)(qr[t] + ks * 32);
            const float4 q1 = *(const float4*)(qr[t] + ks * 32 + 4);
            const float av[8] = {q0.x, q0.y, q0.z, q0.w, q1.x, q1.y, q1.z, q1.w};
#pragma unroll
            for (int j = 0; j < 8; ++j) {
                const unsigned short hi = f2bf(av[j]);
                a_hi[t][j] = (short)hi;
                a_lo[t][j] = (short)f2bf(av[j] - bf2f(hi));
            }
        }

#pragma unroll
        for (int i = 0; i < 5; ++i) {
            const int nt = wt + 4 * i;
            if (nt < 18) {
                const unsigned short* bp = WTs + (size_t)ks * 18432
                                         + (size_t)nt * 512 + g * 128 + c * 8;
                const bf16x8 b_hi = *(const bf16x8*)bp;
                const bf16x8 b_lo = *(const bf16x8*)(bp + 9216);
#pragma unroll
                for (int t = 0; t < 2; ++t) {
                    acc[t][i] = __builtin_amdgcn_mfma_f32_16x16x32_bf16(
                        a_hi[t], b_hi, acc[t][i], 0, 0, 0);
                    acc[t][i] = __builtin_amdgcn_mfma_f32_16x16x32_bf16(
                        a_lo[t], b_hi, acc[t][i], 0, 0, 0);
                    acc[t][i] = __builtin_amdgcn_mfma_f32_16x16x32_bf16(
                        a_hi[t], b_lo, acc[t][i], 0, 0, 0);
                }
            }
        }
    }

#pragma unroll
    for (int i = 0; i < 5; ++i) {
        const int nt = wt + 4 * i;
        if (nt < 18) {
            const int col = nt * 16 + c;
#pragma unroll
            for (int t = 0; t < 2; ++t)
#pragma unroll
                for (int j = 0; j < 4; ++j)
                    logits[(size_t)(row0 + t * 16 + 4 * g + j) * 288 + col] =
                        acc[t][i][j];
        }
    }
}

// ---------------------------------------------------------------------------
// K3: sampler (validated R23).  4-LANE (q,h) groups, 16B corner loads,
// 3 bpermutes/point + imm-offset corner loads; guard absorbs weight-0
// spills.
// ---------------------------------------------------------------------------
__global__ __launch_bounds__(256) void sample_kernel(
    const float* __restrict__ logits,
    const float* __restrict__ ref,
    const float* __restrict__ boff, const float* __restrict__ battn,
    const unsigned short* __restrict__ v0,
    const unsigned short* __restrict__ v1,
    const unsigned short* __restrict__ v2,
    unsigned short* __restrict__ outp)
{
    const int tid  = threadIdx.x;
    const int wv   = tid >> 6;
    const int lane = tid & 63;
    const int qd   = lane >> 2;          // query within wave (0..15)
    const int co   = lane & 3;           // channel quad: ch co*8..co*8+7

    const int id = blockIdx.x;           // 0..5023
    const int h  = id & 7;               // XCD key
    const int m  = id >> 3;              // 0..627
    const int b  = m / 157;
    const int n  = m - b * 157;
    const int q  = n * 64 + wv * 16 + qd;
    if (q >= QLEN) return;               // 4-lane group exits together
    const int qq = b * QLEN + q;

    const float* lgq  = logits + (size_t)qq * 288;
    const int bpbase  = (lane & 60) * 4; // byte index of group lane 0

    // ---- distributed softmax: lane co owns logits {co, 4+co, 8+co} ----
    const float a0l = lgq[192 + h * 12 + co]     + battn[h * 12 + co];
    const float a1l = lgq[192 + h * 12 + 4 + co] + battn[h * 12 + 4 + co];
    const float a2l = lgq[192 + h * 12 + 8 + co] + battn[h * 12 + 8 + co];
    float mx = fmaxf(fmaxf(a0l, a1l), a2l);
#pragma unroll
    for (int msk = 1; msk < 4; msk <<= 1)
        mx = fmaxf(mx, __shfl_xor(mx, msk, 4));
    const float e0 = __expf(a0l - mx);
    const float e1 = __expf(a1l - mx);
    const float e2 = __expf(a2l - mx);
    float sm = e0 + e1 + e2;
#pragma unroll
    for (int msk = 1; msk < 4; msk <<= 1)
        sm += __shfl_xor(sm, msk, 4);
    const float inv = 1.f / sm;

    const float refx = ref[(size_t)qq * 2 + 0];
    const float refy = ref[(size_t)qq * 2 + 1];

    // ---- owner: one point per level; packed weights + biased base ----
    unsigned int opkA[3], opkB[3], opkI[3];
    const float el[3] = {e0, e1, e2};
#pragma unroll
    for (int s = 0; s < 3; ++s) {
        const int pt = s * 4 + co;
        const int Wl = (s == 0) ? 100 : (s == 1) ? 50 : 25;
        const float aw  = el[s] * inv;
        const float lgx = lgq[h * 24 + 2 * pt]     + boff[h * 24 + 2 * pt];
        const float lgy = lgq[h * 24 + 2 * pt + 1] + boff[h * 24 + 2 * pt + 1];
        const float x = (refx + 0.5f * tanh_fast(lgx)) * (float)Wl - 0.5f;
        const float y = (refy + 0.5f * tanh_fast(lgy)) * (float)Wl - 0.5f;
        const float xf = floorf(x), yf = floorf(y);
        const int   x0i = (int)xf, y0i = (int)yf;
        const float wx = x - xf, wy = y - yf;

        float w4[4];
#pragma unroll
        for (int cy = 0; cy < 2; ++cy) {
#pragma unroll
            for (int cx = 0; cx < 2; ++cx) {
                const int xi = x0i + cx, yi = y0i + cy;
                const bool valid = (xi >= 0) & (xi < Wl) & (yi >= 0) & (yi < Wl);
                w4[cy * 2 + cx] = valid
                    ? aw * (cx ? wx : 1.f - wx) * (cy ? wy : 1.f - wy) : 0.f;
            }
        }
        const int xb = min(max(x0i, -1), Wl - 1);
        const int yb = min(max(y0i, -1), Wl - 1);
        opkI[s] = (unsigned int)(yb * Wl + xb + Wl + 1);       // >= 0
        opkA[s] = ((unsigned int)f2bf(w4[0]) << 16) | f2bf(w4[1]);
        opkB[s] = ((unsigned int)f2bf(w4[2]) << 16) | f2bf(w4[3]);
    }

    // ---- gather: 3 bpermutes/point, 16B imm-offset corner loads ----
    float o0 = 0.f, o1 = 0.f, o2 = 0.f, o3 = 0.f;
    float o4 = 0.f, o5 = 0.f, o6 = 0.f, o7 = 0.f;

#pragma unroll
    for (int l = 0; l < 3; ++l) {
        const int Wl = (l == 0) ? 100 : (l == 1) ? 50 : 25;
        const int HW = Wl * Wl;
        const unsigned short* vh =
            ((l == 0) ? v0 : (l == 1) ? v1 : v2) +
            ((size_t)(b * NHEAD + h) * HW) * 32;
        const unsigned short* vha = vh + co * 8 - (size_t)(Wl + 1) * 32;

#pragma unroll
        for (int p = 0; p < 4; ++p) {
            const int a0 = bpbase + 4 * p;    // owner lane of point (l,p)
            const unsigned int pA = (unsigned int)__builtin_amdgcn_ds_bpermute(
                a0, (int)opkA[l]);
            const unsigned int pB = (unsigned int)__builtin_amdgcn_ds_bpermute(
                a0, (int)opkB[l]);
            const int pki = __builtin_amdgcn_ds_bpermute(a0, (int)opkI[l]);

            const float w00 = __uint_as_float(pA & 0xffff0000u);
            const float w01 = __uint_as_float(pA << 16);
            const float w10 = __uint_as_float(pB & 0xffff0000u);
            const float w11 = __uint_as_float(pB << 16);

            const unsigned short* bp = vha + (size_t)pki * 32;
#pragma unroll
            for (int cn = 0; cn < 4; ++cn) {
                const int off = (cn & 1) * 32 + (cn >> 1) * Wl * 32;
                const float cw = (cn == 0) ? w00 : (cn == 1) ? w01
                               : (cn == 2) ? w10 : w11;
                const uint4 u = *(const uint4*)(bp + off);
                o0 = fmaf(cw, __uint_as_float(u.x << 16), o0);
                o1 = fmaf(cw, __uint_as_float(u.x & 0xffff0000u), o1);
                o2 = fmaf(cw, __uint_as_float(u.y << 16), o2);
                o3 = fmaf(cw, __uint_as_float(u.y & 0xffff0000u), o3);
                o4 = fmaf(cw, __uint_as_float(u.z << 16), o4);
                o5 = fmaf(cw, __uint_as_float(u.z & 0xffff0000u), o5);
                o6 = fmaf(cw, __uint_as_float(u.w << 16), o6);
                o7 = fmaf(cw, __uint_as_float(u.w & 0xffff0000u), o7);
            }
        }
    }

    uint4 outv;
    outv.x = (unsigned int)f2bf(o0) | ((unsigned int)f2bf(o1) << 16);
    outv.y = (unsigned int)f2bf(o2) | ((unsigned int)f2bf(o3) << 16);
    outv.z = (unsigned int)f2bf(o4) | ((unsigned int)f2bf(o5) << 16);
    outv.w = (unsigned int)f2bf(o6) | ((unsigned int)f2bf(o7) << 16);
    *(uint4*)(outp + (size_t)qq * 256 + h * 32 + co * 8) = outv;
}

// ---------------------------------------------------------------------------
// K4: output projection via bf16 MFMA (validated R7).
// ---------------------------------------------------------------------------
__global__ __launch_bounds__(256) void outproj_kernel(
    const unsigned short* __restrict__ A, const unsigned short* __restrict__ WoT,
    const float* __restrict__ bo, float* __restrict__ out)
{
    const int tid  = threadIdx.x;
    const int wave = tid >> 6;
    const int lane = tid & 63;
    const int c    = lane & 15;
    const int g    = lane >> 4;
    const int row0 = blockIdx.x * 64;
    const int n0   = wave * 64;

    f32x4 acc[4][4];
#pragma unroll
    for (int mt = 0; mt < 4; ++mt)
#pragma unroll
        for (int nt = 0; nt < 4; ++nt)
            acc[mt][nt] = (f32x4){0.f, 0.f, 0.f, 0.f};

    const unsigned short* Abase = A   + (size_t)(row0 + c) * 256 + 8 * g;
    const unsigned short* Bbase = WoT + (size_t)(n0   + c) * 256 + 8 * g;

#pragma unroll
    for (int ks = 0; ks < 8; ++ks) {
        bf16x8 a[4], bvec[4];
#pragma unroll
        for (int t = 0; t < 4; ++t) {
            a[t]    = *(const bf16x8*)(Abase + (size_t)t * 16 * 256 + ks * 32);
            bvec[t] = *(const bf16x8*)(Bbase + (size_t)t * 16 * 256 + ks * 32);
        }
#pragma unroll
        for (int mt = 0; mt < 4; ++mt)
#pragma unroll
            for (int nt = 0; nt < 4; ++nt)
                acc[mt][nt] = __builtin_amdgcn_mfma_f32_16x16x32_bf16(
                    a[mt], bvec[nt], acc[mt][nt], 0, 0, 0);
    }

#pragma unroll
    for (int nt = 0; nt < 4; ++nt) {
        const int col  = n0 + nt * 16 + c;
        const float bias = bo[col];
#pragma unroll
        for (int mt = 0; mt < 4; ++mt) {
#pragma unroll
            for (int j = 0; j < 4; ++j) {
                const int row = row0 + mt * 16 + g * 4 + j;
                out[(size_t)row * 256 + col] = acc[mt][nt][j] + bias;
            }
        }
    }
}

// ---------------------------------------------------------------------------
extern "C" void kernel_launch(void* const* d_in, const int* in_sizes, int n_in,
                              void* d_out, int out_size, void* d_ws, size_t ws_size,
                              hipStream_t stream)
{
    const float* query  = (const float*)d_in[0];
    const float* value0 = (const float*)d_in[1];
    const float* value1 = (const float*)d_in[2];
    const float* value2 = (const float*)d_in[3];
    const float* refpts = (const float*)d_in[4];
    const float* Woff   = (const float*)d_in[5];
    const float* boff   = (const float*)d_in[6];
    const float* Wattn  = (const float*)d_in[7];
    const float* battn  = (const float*)d_in[8];
    const float* Wval   = (const float*)d_in[9];
    const float* bval   = (const float*)d_in[10];
    const float* Wout   = (const float*)d_in[11];
    const float* bout   = (const float*)d_in[12];
    float* out = (float*)d_out;

    // workspace: logits 46.08 + GUARD 8KB + v 26.88 + A_bf 20.48 + weights
    // ~0.7 = ~94.2 MB.  GUARD absorbs weight-0 front-spill reads.
    float*          logits = (float*)d_ws;
    unsigned short* guard = (unsigned short*)(logits + (size_t)NQ * 288);
    unsigned short* v0   = guard + 4096;              // 8 KB guard
    unsigned short* v1   = v0 + (size_t)BATCH * 10000 * 256;
    unsigned short* v2   = v1 + (size_t)BATCH * 2500  * 256;
    unsigned short* A_bf = v2 + (size_t)BATCH * 625   * 256;
    unsigned short* WoT  = A_bf + (size_t)NQ * 256;
    unsigned short* WTs  = WoT + (size_t)256 * 256;        // 147456 shorts
    unsigned short* WvSh = WTs + (size_t)147456;
    unsigned short* WvSl = WvSh + (size_t)65536;

    wprep_kernel<<<800, 256, 0, stream>>>(Woff, Wattn, Wout, Wval,
                                          WTs, WoT, WvSh, WvSl);

    vproj_kernel<<<dim3(412, BATCH), 256, 0, stream>>>(
        value0, value1, value2, WvSh, WvSl, bval, v0, v1, v2);

    qgemm_kernel<<<NQ / 32, 256, 0, stream>>>(query, WTs, logits);

    sample_kernel<<<8 * 157 * BATCH, 256, 0, stream>>>(
        logits, refpts, boff, battn, v0, v1, v2, A_bf);

    outproj_kernel<<<NQ / 64, 256, 0, stream>>>(A_bf, WoT, bout, out);
}

// Round 25
// 189.657 us; speedup vs baseline: 1.0471x; 1.0000x over previous
//
#include <hip/hip_runtime.h>
#include <math.h>

#define DMODEL 256
#define NHEAD 8
#define NLVL 3
#define NPTS 4
#define HDIM 32
#define QLEN 10000
#define BATCH 4
#define NQ (BATCH * QLEN)

typedef __attribute__((ext_vector_type(8))) short bf16x8;
typedef __attribute__((ext_vector_type(4))) float f32x4;

__device__ __forceinline__ float tanh_fast(float x)
{
    const float ax = fabsf(x);
    const float e  = __expf(-2.f * ax);
    const float t  = (1.f - e) / (1.f + e);
    return copysignf(t, x);
}

__device__ __forceinline__ unsigned short f2bf(float f)
{
    unsigned int u = __float_as_uint(f);
    u = (u + 0x7FFFu + ((u >> 16) & 1u)) >> 16;
    return (unsigned short)u;
}

__device__ __forceinline__ float bf2f(unsigned short s)
{
    return __uint_as_float(((unsigned int)s) << 16);
}

// ---------------------------------------------------------------------------
// K0: weight prep (once).  Pre-swizzled layouts (validated R18).
// ---------------------------------------------------------------------------
__global__ __launch_bounds__(256) void wprep_kernel(
    const float* __restrict__ Woff, const float* __restrict__ Wattn,
    const float* __restrict__ Wout, const float* __restrict__ Wval,
    unsigned short* __restrict__ WTs, unsigned short* __restrict__ WoT,
    unsigned short* __restrict__ WvSh, unsigned short* __restrict__ WvSl)
{
    const int k  = threadIdx.x;
    const int n  = blockIdx.x;
    const int ks = k >> 5;
    const int g  = (k >> 3) & 3;
    const int j  = k & 7;
    if (n < 288) {
        const float w = (n < 192) ? Woff[(size_t)k * 192 + n]
                                  : Wattn[(size_t)k * 96 + (n - 192)];
        const unsigned short hi = f2bf(w);
        const unsigned short lo = f2bf(w - bf2f(hi));
        const int nt = n >> 4, c = n & 15;
        const size_t base = (size_t)ks * 18432 + (size_t)nt * 512
                          + g * 128 + c * 8 + j;
        WTs[base]        = hi;    // hl = 0
        WTs[base + 9216] = lo;    // hl = 1 (offset 9216 shorts)
    } else if (n < 544) {
        const int nn = n - 288;
        WoT[(size_t)nn * 256 + k] = f2bf(Wout[(size_t)k * 256 + nn]);
    } else {
        const int nn = n - 544;
        const float w = Wval[(size_t)k * 256 + nn];
        const unsigned short hi = f2bf(w);
        const int nc = nn >> 4, c = nn & 15;
        const size_t idx = (size_t)nc * 4096 + (size_t)ks * 512
                         + g * 128 + c * 8 + j;
        WvSh[idx] = hi;
        WvSl[idx] = f2bf(w - bf2f(hi));
    }
}

// ---------------------------------------------------------------------------
// K1: value projection via bf16 MFMA, 32-pos tiles (validated R18).
// Output HEAD-MAJOR v[b][h][pos][32].
// ---------------------------------------------------------------------------
__global__ __launch_bounds__(256) void vproj_kernel(
    const float* __restrict__ feat0, const float* __restrict__ feat1,
    const float* __restrict__ feat2,
    const unsigned short* __restrict__ WvSh, const unsigned short* __restrict__ WvSl,
    const float* __restrict__ bv,
    unsigned short* __restrict__ v0, unsigned short* __restrict__ v1,
    unsigned short* __restrict__ v2)
{
    __shared__ short As[32 * 32 * 8];   // [kc][pos][8] = 16 KB

    const int bx = blockIdx.x;
    const int b  = blockIdx.y;

    const float* feat;
    unsigned short* vout;
    int HW, pos0;
    if (bx < 313)      { feat = feat0; vout = v0; HW = 10000; pos0 = bx * 32; }
    else if (bx < 392) { feat = feat1; vout = v1; HW = 2500;  pos0 = (bx - 313) * 32; }
    else               { feat = feat2; vout = v2; HW = 625;   pos0 = (bx - 392) * 32; }

    const int tid  = threadIdx.x;
    const int wv   = tid >> 6;
    const int lane = tid & 63;
    const int c    = lane & 15;
    const int g    = lane >> 4;

    const int sp  = tid & 31;
    const int kc8 = tid >> 5;
    const bool pv = (pos0 + sp) < HW;
    const float* fcol = feat + (size_t)b * DMODEL * HW + pos0 + sp;

#pragma unroll
    for (int i = 0; i < 4; ++i) {
        const int kc = kc8 + 8 * i;
        short h8[8];
#pragma unroll
        for (int j = 0; j < 8; ++j) {
            const float f = pv ? fcol[(size_t)(kc * 8 + j) * HW] : 0.f;
            h8[j] = (short)f2bf(f);
        }
        *(bf16x8*)&As[((size_t)kc * 32 + sp) * 8] = *(bf16x8*)h8;
    }
    __syncthreads();

    f32x4 acc[2][4];
#pragma unroll
    for (int mt = 0; mt < 2; ++mt)
#pragma unroll
        for (int nt = 0; nt < 4; ++nt)
            acc[mt][nt] = (f32x4){0.f, 0.f, 0.f, 0.f};

#pragma unroll
    for (int ks = 0; ks < 8; ++ks) {
        bf16x8 a[2];
#pragma unroll
        for (int mt = 0; mt < 2; ++mt)
            a[mt] = *(const bf16x8*)&As[((size_t)(ks * 4 + g) * 32 + mt * 16 + c) * 8];
        bf16x8 bh[4], bl[4];
#pragma unroll
        for (int nt = 0; nt < 4; ++nt) {
            const size_t off = (size_t)(wv * 4 + nt) * 4096 + (size_t)ks * 512
                             + g * 128 + c * 8;
            bh[nt] = *(const bf16x8*)(WvSh + off);
            bl[nt] = *(const bf16x8*)(WvSl + off);
        }
#pragma unroll
        for (int mt = 0; mt < 2; ++mt)
#pragma unroll
            for (int nt = 0; nt < 4; ++nt) {
                acc[mt][nt] = __builtin_amdgcn_mfma_f32_16x16x32_bf16(
                    a[mt], bh[nt], acc[mt][nt], 0, 0, 0);
                acc[mt][nt] = __builtin_amdgcn_mfma_f32_16x16x32_bf16(
                    a[mt], bl[nt], acc[mt][nt], 0, 0, 0);
            }
    }

    unsigned short* vbp = vout + (size_t)b * NHEAD * HW * 32;
#pragma unroll
    for (int nt = 0; nt < 4; ++nt) {
        const int col  = wv * 64 + nt * 16 + c;
        const int hh   = col >> 5;
        const int cc   = col & 31;
        const float bias = bv[col];
#pragma unroll
        for (int mt = 0; mt < 2; ++mt) {
#pragma unroll
            for (int j = 0; j < 4; ++j) {
                const int p = mt * 16 + g * 4 + j;
                if (pos0 + p < HW)
                    vbp[((size_t)hh * HW + pos0 + p) * 32 + cc] =
                        f2bf(acc[mt][nt][j] + bias);
            }
        }
    }
}

// ---------------------------------------------------------------------------
// K2: query-side GEMM, direct-global B, 32 rows/block (validated R19/R22).
// ---------------------------------------------------------------------------
__global__ __launch_bounds__(256) void qgemm_kernel(
    const float* __restrict__ query,
    const unsigned short* __restrict__ WTs,
    float* __restrict__ logits)
{
    const int tid  = threadIdx.x;
    const int wt   = tid >> 6;
    const int lane = tid & 63;
    const int c    = lane & 15;
    const int g    = lane >> 4;
    const int row0 = blockIdx.x * 32;

    const float* qr[2];
#pragma unroll
    for (int t = 0; t < 2; ++t)
        qr[t] = query + (size_t)(row0 + t * 16 + c) * 256 + 8 * g;

    f32x4 acc[2][5];
#pragma unroll
    for (int t = 0; t < 2; ++t)
#pragma unroll
        for (int i = 0; i < 5; ++i) acc[t][i] = (f32x4){0.f, 0.f, 0.f, 0.f};

#pragma unroll
    for (int ks = 0; ks < 8; ++ks) {
        bf16x8 a_hi[2], a_lo[2];
#pragma unroll
        for (int t = 0; t < 2; ++t) {
            const float4 q0 = *(const float4*)(qr[t] + ks * 32);
            const float4 q1 = *(const float4*)(qr[t] + ks * 32 + 4);
            const float av[8] = {q0.x, q0.y, q0.z, q0.w, q1.x, q1.y, q1.z, q1.w};
#pragma unroll
            for (int j = 0; j < 8; ++j) {
                const unsigned short hi = f2bf(av[j]);
                a_hi[t][j] = (short)hi;
                a_lo[t][j] = (short)f2bf(av[j] - bf2f(hi));
            }
        }

#pragma unroll
        for (int i = 0; i < 5; ++i) {
            const int nt = wt + 4 * i;
            if (nt < 18) {
                const unsigned short* bp = WTs + (size_t)ks * 18432
                                         + (size_t)nt * 512 + g * 128 + c * 8;
                const bf16x8 b_hi = *(const bf16x8*)bp;
                const bf16x8 b_lo = *(const bf16x8*)(bp + 9216);
#pragma unroll
                for (int t = 0; t < 2; ++t) {
                    acc[t][i] = __builtin_amdgcn_mfma_f32_16x16x32_bf16(
                        a_hi[t], b_hi, acc[t][i], 0, 0, 0);
                    acc[t][i] = __builtin_amdgcn_mfma_f32_16x16x32_bf16(
                        a_lo[t], b_hi, acc[t][i], 0, 0, 0);
                    acc[t][i] = __builtin_amdgcn_mfma_f32_16x16x32_bf16(
                        a_hi[t], b_lo, acc[t][i], 0, 0, 0);
                }
            }
        }
    }

#pragma unroll
    for (int i = 0; i < 5; ++i) {
        const int nt = wt + 4 * i;
        if (nt < 18) {
            const int col = nt * 16 + c;
#pragma unroll
            for (int t = 0; t < 2; ++t)
#pragma unroll
                for (int j = 0; j < 4; ++j)
                    logits[(size_t)(row0 + t * 16 + 4 * g + j) * 288 + col] =
                        acc[t][i][j];
        }
    }
}

// ---------------------------------------------------------------------------
// K3: sampler (R23 structure) with EXPLICIT MEMORY-LEVEL PARALLELISM:
// per level, all 12 bpermutes issue together, then all 16 corner loads
// (4 points x 4 corners) live simultaneously in u[4][4], then unpack+FMA.
// Forces the register file to hold 16 in-flight loads (vs compiler's
// minimal-VGPR serialization at VGPR=32).  Math bit-identical to R24.
// ---------------------------------------------------------------------------
__global__ __launch_bounds__(256) void sample_kernel(
    const float* __restrict__ logits,
    const float* __restrict__ ref,
    const float* __restrict__ boff, const float* __restrict__ battn,
    const unsigned short* __restrict__ v0,
    const unsigned short* __restrict__ v1,
    const unsigned short* __restrict__ v2,
    unsigned short* __restrict__ outp)
{
    const int tid  = threadIdx.x;
    const int wv   = tid >> 6;
    const int lane = tid & 63;
    const int qd   = lane >> 2;          // query within wave (0..15)
    const int co   = lane & 3;           // channel quad: ch co*8..co*8+7

    const int id = blockIdx.x;           // 0..5023
    const int h  = id & 7;               // XCD key
    const int m  = id >> 3;              // 0..627
    const int b  = m / 157;
    const int n  = m - b * 157;
    const int q  = n * 64 + wv * 16 + qd;
    if (q >= QLEN) return;               // 4-lane group exits together
    const int qq = b * QLEN + q;

    const float* lgq  = logits + (size_t)qq * 288;
    const int bpbase  = (lane & 60) * 4; // byte index of group lane 0

    // ---- distributed softmax: lane co owns logits {co, 4+co, 8+co} ----
    const float a0l = lgq[192 + h * 12 + co]     + battn[h * 12 + co];
    const float a1l = lgq[192 + h * 12 + 4 + co] + battn[h * 12 + 4 + co];
    const float a2l = lgq[192 + h * 12 + 8 + co] + battn[h * 12 + 8 + co];
    float mx = fmaxf(fmaxf(a0l, a1l), a2l);
#pragma unroll
    for (int msk = 1; msk < 4; msk <<= 1)
        mx = fmaxf(mx, __shfl_xor(mx, msk, 4));
    const float e0 = __expf(a0l - mx);
    const float e1 = __expf(a1l - mx);
    const float e2 = __expf(a2l - mx);
    float sm = e0 + e1 + e2;
#pragma unroll
    for (int msk = 1; msk < 4; msk <<= 1)
        sm += __shfl_xor(sm, msk, 4);
    const float inv = 1.f / sm;

    const float refx = ref[(size_t)qq * 2 + 0];
    const float refy = ref[(size_t)qq * 2 + 1];

    // ---- owner: one point per level; packed weights + biased base ----
    unsigned int opkA[3], opkB[3], opkI[3];
    const float el[3] = {e0, e1, e2};
#pragma unroll
    for (int s = 0; s < 3; ++s) {
        const int pt = s * 4 + co;
        const int Wl = (s == 0) ? 100 : (s == 1) ? 50 : 25;
        const float aw  = el[s] * inv;
        const float lgx = lgq[h * 24 + 2 * pt]     + boff[h * 24 + 2 * pt];
        const float lgy = lgq[h * 24 + 2 * pt + 1] + boff[h * 24 + 2 * pt + 1];
        const float x = (refx + 0.5f * tanh_fast(lgx)) * (float)Wl - 0.5f;
        const float y = (refy + 0.5f * tanh_fast(lgy)) * (float)Wl - 0.5f;
        const float xf = floorf(x), yf = floorf(y);
        const int   x0i = (int)xf, y0i = (int)yf;
        const float wx = x - xf, wy = y - yf;

        float w4[4];
#pragma unroll
        for (int cy = 0; cy < 2; ++cy) {
#pragma unroll
            for (int cx = 0; cx < 2; ++cx) {
                const int xi = x0i + cx, yi = y0i + cy;
                const bool valid = (xi >= 0) & (xi < Wl) & (yi >= 0) & (yi < Wl);
                w4[cy * 2 + cx] = valid
                    ? aw * (cx ? wx : 1.f - wx) * (cy ? wy : 1.f - wy) : 0.f;
            }
        }
        const int xb = min(max(x0i, -1), Wl - 1);
        const int yb = min(max(y0i, -1), Wl - 1);
        opkI[s] = (unsigned int)(yb * Wl + xb + Wl + 1);       // >= 0
        opkA[s] = ((unsigned int)f2bf(w4[0]) << 16) | f2bf(w4[1]);
        opkB[s] = ((unsigned int)f2bf(w4[2]) << 16) | f2bf(w4[3]);
    }

    // ---- gather: per level, 12 bpermutes then 16 in-flight loads ----
    float o0 = 0.f, o1 = 0.f, o2 = 0.f, o3 = 0.f;
    float o4 = 0.f, o5 = 0.f, o6 = 0.f, o7 = 0.f;

#pragma unroll
    for (int l = 0; l < 3; ++l) {
        const int Wl = (l == 0) ? 100 : (l == 1) ? 50 : 25;
        const int HW = Wl * Wl;
        const unsigned short* vh =
            ((l == 0) ? v0 : (l == 1) ? v1 : v2) +
            ((size_t)(b * NHEAD + h) * HW) * 32;
        const unsigned short* vha = vh + co * 8 - (size_t)(Wl + 1) * 32;

        // (1) all bpermutes for this level
        unsigned int pA[4], pB[4];
        int pki[4];
#pragma unroll
        for (int p = 0; p < 4; ++p) {
            const int a0 = bpbase + 4 * p;
            pA[p]  = (unsigned int)__builtin_amdgcn_ds_bpermute(a0, (int)opkA[l]);
            pB[p]  = (unsigned int)__builtin_amdgcn_ds_bpermute(a0, (int)opkB[l]);
            pki[p] = __builtin_amdgcn_ds_bpermute(a0, (int)opkI[l]);
        }

        // (2) all 16 corner loads in flight
        uint4 u[4][4];
#pragma unroll
        for (int p = 0; p < 4; ++p) {
            const unsigned short* bp = vha + (size_t)pki[p] * 32;
            u[p][0] = *(const uint4*)(bp);
            u[p][1] = *(const uint4*)(bp + 32);
            u[p][2] = *(const uint4*)(bp + Wl * 32);
            u[p][3] = *(const uint4*)(bp + Wl * 32 + 32);
        }

        // (3) unpack + FMA
#pragma unroll
        for (int p = 0; p < 4; ++p) {
            const float wc[4] = {
                __uint_as_float(pA[p] & 0xffff0000u),
                __uint_as_float(pA[p] << 16),
                __uint_as_float(pB[p] & 0xffff0000u),
                __uint_as_float(pB[p] << 16)
            };
#pragma unroll
            for (int cn = 0; cn < 4; ++cn) {
                const float cw = wc[cn];
                const uint4 uu = u[p][cn];
                o0 = fmaf(cw, __uint_as_float(uu.x << 16), o0);
                o1 = fmaf(cw, __uint_as_float(uu.x & 0xffff0000u), o1);
                o2 = fmaf(cw, __uint_as_float(uu.y << 16), o2);
                o3 = fmaf(cw, __uint_as_float(uu.y & 0xffff0000u), o3);
                o4 = fmaf(cw, __uint_as_float(uu.z << 16), o4);
                o5 = fmaf(cw, __uint_as_float(uu.z & 0xffff0000u), o5);
                o6 = fmaf(cw, __uint_as_float(uu.w << 16), o6);
                o7 = fmaf(cw, __uint_as_float(uu.w & 0xffff0000u), o7);
            }
        }
    }

    uint4 outv;
    outv.x = (unsigned int)f2bf(o0) | ((unsigned int)f2bf(o1) << 16);
    outv.y = (unsigned int)f2bf(o2) | ((unsigned int)f2bf(o3) << 16);
    outv.z = (unsigned int)f2bf(o4) | ((unsigned int)f2bf(o5) << 16);
    outv.w = (unsigned int)f2bf(o6) | ((unsigned int)f2bf(o7) << 16);
    *(uint4*)(outp + (size_t)qq * 256 + h * 32 + co * 8) = outv;
}

// ---------------------------------------------------------------------------
// K4: output projection via bf16 MFMA (validated R7).
// ---------------------------------------------------------------------------
__global__ __launch_bounds__(256) void outproj_kernel(
    const unsigned short* __restrict__ A, const unsigned short* __restrict__ WoT,
    const float* __restrict__ bo, float* __restrict__ out)
{
    const int tid  = threadIdx.x;
    const int wave = tid >> 6;
    const int lane = tid & 63;
    const int c    = lane & 15;
    const int g    = lane >> 4;
    const int row0 = blockIdx.x * 64;
    const int n0   = wave * 64;

    f32x4 acc[4][4];
#pragma unroll
    for (int mt = 0; mt < 4; ++mt)
#pragma unroll
        for (int nt = 0; nt < 4; ++nt)
            acc[mt][nt] = (f32x4){0.f, 0.f, 0.f, 0.f};

    const unsigned short* Abase = A   + (size_t)(row0 + c) * 256 + 8 * g;
    const unsigned short* Bbase = WoT + (size_t)(n0   + c) * 256 + 8 * g;

#pragma unroll
    for (int ks = 0; ks < 8; ++ks) {
        bf16x8 a[4], bvec[4];
#pragma unroll
        for (int t = 0; t < 4; ++t) {
            a[t]    = *(const bf16x8*)(Abase + (size_t)t * 16 * 256 + ks * 32);
            bvec[t] = *(const bf16x8*)(Bbase + (size_t)t * 16 * 256 + ks * 32);
        }
#pragma unroll
        for (int mt = 0; mt < 4; ++mt)
#pragma unroll
            for (int nt = 0; nt < 4; ++nt)
                acc[mt][nt] = __builtin_amdgcn_mfma_f32_16x16x32_bf16(
                    a[mt], bvec[nt], acc[mt][nt], 0, 0, 0);
    }

#pragma unroll
    for (int nt = 0; nt < 4; ++nt) {
        const int col  = n0 + nt * 16 + c;
        const float bias = bo[col];
#pragma unroll
        for (int mt = 0; mt < 4; ++mt) {
#pragma unroll
            for (int j = 0; j < 4; ++j) {
                const int row = row0 + mt * 16 + g * 4 + j;
                out[(size_t)row * 256 + col] = acc[mt][nt][j] + bias;
            }
        }
    }
}

// ---------------------------------------------------------------------------
extern "C" void kernel_launch(void* const* d_in, const int* in_sizes, int n_in,
                              void* d_out, int out_size, void* d_ws, size_t ws_size,
                              hipStream_t stream)
{
    const float* query  = (const float*)d_in[0];
    const float* value0 = (const float*)d_in[1];
    const float* value1 = (const float*)d_in[2];
    const float* value2 = (const float*)d_in[3];
    const float* refpts = (const float*)d_in[4];
    const float* Woff   = (const float*)d_in[5];
    const float* boff   = (const float*)d_in[6];
    const float* Wattn  = (const float*)d_in[7];
    const float* battn  = (const float*)d_in[8];
    const float* Wval   = (const float*)d_in[9];
    const float* bval   = (const float*)d_in[10];
    const float* Wout   = (const float*)d_in[11];
    const float* bout   = (const float*)d_in[12];
    float* out = (float*)d_out;

    // workspace: logits 46.08 + GUARD 8KB + v 26.88 + A_bf 20.48 + weights
    // ~0.7 = ~94.2 MB.  GUARD absorbs weight-0 front-spill reads.
    float*          logits = (float*)d_ws;
    unsigned short* guard = (unsigned short*)(logits + (size_t)NQ * 288);
    unsigned short* v0   = guard + 4096;              // 8 KB guard
    unsigned short* v1   = v0 + (size_t)BATCH * 10000 * 256;
    unsigned short* v2   = v1 + (size_t)BATCH * 2500  * 256;
    unsigned short* A_bf = v2 + (size_t)BATCH * 625   * 256;
    unsigned short* WoT  = A_bf + (size_t)NQ * 256;
    unsigned short* WTs  = WoT + (size_t)256 * 256;        // 147456 shorts
    unsigned short* WvSh = WTs + (size_t)147456;
    unsigned short* WvSl = WvSh + (size_t)65536;

    wprep_kernel<<<800, 256, 0, stream>>>(Woff, Wattn, Wout, Wval,
                                          WTs, WoT, WvSh, WvSl);

    vproj_kernel<<<dim3(412, BATCH), 256, 0, stream>>>(
        value0, value1, value2, WvSh, WvSl, bval, v0, v1, v2);

    qgemm_kernel<<<NQ / 32, 256, 0, stream>>>(query, WTs, logits);

    sample_kernel<<<8 * 157 * BATCH, 256, 0, stream>>>(
        logits, refpts, boff, battn, v0, v1, v2, A_bf);

    outproj_kernel<<<NQ / 64, 256, 0, stream>>>(A_bf, WoT, bout, out);
}